// Round 1
// baseline (237.801 us; speedup 1.0000x reference)
//
#include <hip/hip_runtime.h>

typedef unsigned short u16;
typedef unsigned int   u32;
typedef __attribute__((ext_vector_type(8))) short short8;   // 8 bf16 (4 VGPRs)
typedef __attribute__((ext_vector_type(4))) float f32x4;    // MFMA C/D

// ---- bf16 helpers (bf16 = top 16 bits of fp32; half-up rounding) ----
__device__ __forceinline__ float bl(u32 u){ union{u32 i; float f;} c; c.i = u << 16; return c.f; }
__device__ __forceinline__ float bh(u32 u){ union{u32 i; float f;} c; c.i = u & 0xffff0000u; return c.f; }
__device__ __forceinline__ u16 f2b(float f){
  union{float f; u32 i;} c; c.f = f;
  return (u16)((c.i + 0x8000u) >> 16);
}
__device__ __forceinline__ u32 pk2(float a, float b){
  union{float f; u32 i;} x, y; x.f = a; y.f = b;
  return ((x.i + 0x8000u) >> 16) | ((y.i + 0x8000u) & 0xffff0000u);
}
// accumulate: 4 bf16 x-values (packed) + 4 f32 emb values
__device__ __forceinline__ void accf(float* a, uint2 xq, float4 ef){
  a[0] += bl(xq.x) + ef.x;  a[1] += bh(xq.x) + ef.y;
  a[2] += bl(xq.y) + ef.z;  a[3] += bh(xq.y) + ef.w;
}

// one-wave exclusive scan of bsum[0..nb) into sPre (call with t < 64)
__device__ __forceinline__ void wave_scan_bsum(
    const int* __restrict__ bsum, int nb, int* __restrict__ sPre, int t)
{
  int carry = 0;
  for (int c0 = 0; c0 < nb; c0 += 64) {
    int idx = c0 + t;
    int b = (idx < nb) ? bsum[idx] : 0;
    int v = b;
    #pragma unroll
    for (int d = 1; d < 64; d <<= 1) {
      int u = __shfl_up(v, d);
      if (t >= d) v += u;
    }
    if (idx < nb) sPre[idx] = carry + v - b;   // exclusive
    carry += __shfl(v, 63);
  }
}

// =====================================================================
// k_setup: transpose weights to bf16 n-major WT[n][k], build combined
// f32 emb table embF[36][128], zero cnt.
// =====================================================================
__global__ __launch_bounds__(256) void k_setup(
    const float* __restrict__ Wenc, const float* __restrict__ W1,
    const float* __restrict__ W2, const float* __restrict__ e1,
    const float* __restrict__ e2, u16* __restrict__ WencT,
    u16* __restrict__ W1T, u16* __restrict__ W2T,
    float* __restrict__ embF, int* __restrict__ cnt, int N)
{
  int i = blockIdx.x * 256 + threadIdx.x;
  if (i < 16384) {                        // WencT: [128 n][128 k]
    int n = i >> 7, k = i & 127;
    WencT[i] = f2b(Wenc[k * 128 + n]);
  } else if (i < 49152) {                 // W1T: [256 n][128 k]
    int j = i - 16384;
    int n = j >> 7, k = j & 127;
    W1T[j] = f2b(W1[k * 256 + n]);
  } else if (i < 81920) {                 // W2T: [128 n][256 k]
    int j = i - 49152;
    int n = j >> 8, k = j & 255;
    W2T[j] = f2b(W2[k * 128 + n]);
  } else if (i < 81920 + 4608) {          // embF: [36 combo][128 k] f32
    int j = i - 81920;
    int comb = j >> 7, k = j & 127;
    int c1 = comb / 6, c2 = comb - c1 * 6;
    embF[j] = e1[c1 * 128 + k] + e2[c2 * 128 + k];
  } else {
    int j = i - 81920 - 4608;
    if (j < N) cnt[j] = 0;
  }
}

// =====================================================================
// k_enc_count: blocks [0, encBlocks) -> xenc = bf16(PReLU(x) @ W_enc)
//              blocks [encBlocks,..) -> degree histogram + per-edge rank
// (enc FIRST so the many latency-bound count blocks hide it)
// =====================================================================
__global__ __launch_bounds__(256) void k_enc_count(
    const float* __restrict__ x, const float* __restrict__ pa,
    const u16* __restrict__ WT, u16* __restrict__ xenc, int N,
    const int* __restrict__ ei, int* __restrict__ cnt,
    int* __restrict__ rank, int E, int encBlocks)
{
  if ((int)blockIdx.x >= encBlocks) {
    int e = ((int)blockIdx.x - encBlocks) * 256 + threadIdx.x;
    if (e < E) rank[e] = atomicAdd(&cnt[ei[E + e]], 1);
    return;
  }

  const int K = 128, SK = 136, NT = 8;
  __shared__ u16 sB[128 * SK];           // 34 KB

  const int t = threadIdx.x;
  #pragma unroll
  for (int j = 0; j < 8; j++) {
    int i = t + 256 * j;
    int n = i >> 4, k8 = i & 15;
    *(uint4*)&sB[n * SK + k8 * 8] = *(const uint4*)&WT[n * K + k8 * 8];
  }
  __syncthreads();

  const float slope = pa[0];
  const int lane = t & 63, wave = t >> 6, quad = lane >> 4, l16 = lane & 15;
  const int m0 = blockIdx.x * 128 + wave * 32;
  if (m0 >= N) return;

  f32x4 acc[2][NT];
  #pragma unroll
  for (int mr = 0; mr < 2; mr++)
    #pragma unroll
    for (int nt = 0; nt < NT; nt++) acc[mr][nt] = (f32x4){0.f, 0.f, 0.f, 0.f};

  #pragma unroll
  for (int ks = 0; ks < 4; ks++) {
    const int k0 = ks * 32 + quad * 8;
    union { u32 u[4]; short8 s; } a[2];
    #pragma unroll
    for (int mr = 0; mr < 2; mr++) {
      int row = m0 + mr * 16 + l16; row = min(row, N - 1);
      const float4* ap = (const float4*)&x[(size_t)row * 128 + k0];
      float4 f0 = ap[0], f1 = ap[1];
      float v0 = f0.x > 0.f ? f0.x : slope * f0.x;
      float v1 = f0.y > 0.f ? f0.y : slope * f0.y;
      float v2 = f0.z > 0.f ? f0.z : slope * f0.z;
      float v3 = f0.w > 0.f ? f0.w : slope * f0.w;
      float v4 = f1.x > 0.f ? f1.x : slope * f1.x;
      float v5 = f1.y > 0.f ? f1.y : slope * f1.y;
      float v6 = f1.z > 0.f ? f1.z : slope * f1.z;
      float v7 = f1.w > 0.f ? f1.w : slope * f1.w;
      a[mr].u[0] = pk2(v0, v1); a[mr].u[1] = pk2(v2, v3);
      a[mr].u[2] = pk2(v4, v5); a[mr].u[3] = pk2(v6, v7);
    }
    #pragma unroll
    for (int nt = 0; nt < NT; nt++) {
      short8 b = *(const short8*)&sB[(nt * 16 + l16) * SK + k0];
      acc[0][nt] = __builtin_amdgcn_mfma_f32_16x16x32_bf16(a[0].s, b, acc[0][nt], 0, 0, 0);
      acc[1][nt] = __builtin_amdgcn_mfma_f32_16x16x32_bf16(a[1].s, b, acc[1][nt], 0, 0, 0);
    }
  }

  #pragma unroll
  for (int mr = 0; mr < 2; mr++)
    #pragma unroll
    for (int nt = 0; nt < NT; nt++) {
      int col = nt * 16 + l16;
      #pragma unroll
      for (int r = 0; r < 4; r++) {
        int row = m0 + mr * 16 + quad * 4 + r;
        if (row < N) xenc[(size_t)row * 128 + col] = f2b(acc[mr][nt][r]);
      }
    }
}

// =====================================================================
// k_scan_block: per-1024-chunk exclusive scan of cnt -> offs, + bsum.
// (bsum prefix is folded into k_fill / k_gather - no scan_add kernel)
// =====================================================================
__global__ __launch_bounds__(256) void k_scan_block(
    const int* __restrict__ cnt, int* __restrict__ offs,
    int* __restrict__ bsum, int n)
{
  __shared__ int sS[256];
  const int b = blockIdx.x, t = threadIdx.x;
  const int i0 = b * 1024 + t * 4;
  int4 v = make_int4(0, 0, 0, 0);
  if (i0 + 3 < n) v = *(const int4*)&cnt[i0];
  else {
    if (i0     < n) v.x = cnt[i0];
    if (i0 + 1 < n) v.y = cnt[i0 + 1];
    if (i0 + 2 < n) v.z = cnt[i0 + 2];
  }
  int s = v.x + v.y + v.z + v.w;
  sS[t] = s;
  __syncthreads();
  for (int d = 1; d < 256; d <<= 1) {
    int val = (t >= d) ? sS[t - d] : 0;
    __syncthreads();
    sS[t] += val;
    __syncthreads();
  }
  int ex = sS[t] - s;
  if (t == 255) bsum[b] = sS[t];
  int o0 = ex, o1 = o0 + v.x, o2 = o1 + v.y, o3 = o2 + v.z;
  if (i0     < n) offs[i0]     = o0;
  if (i0 + 1 < n) offs[i0 + 1] = o1;
  if (i0 + 2 < n) offs[i0 + 2] = o2;
  if (i0 + 3 < n) offs[i0 + 3] = o3;
}

// =====================================================================
// k_fill: atomic-free scatter of packed edge records (uses rank).
// rec = src | (a1*6+a2) << 26.  Adds bsum prefix inline.
// =====================================================================
__global__ __launch_bounds__(256) void k_fill(
    const int* __restrict__ ei, const int* __restrict__ ea,
    const int* __restrict__ offs, const int* __restrict__ rank,
    const int* __restrict__ bsum, int nb,
    u32* __restrict__ recs, int E)
{
  __shared__ int sPre[256];
  const int t = threadIdx.x;
  if (t < 64) wave_scan_bsum(bsum, nb, sPre, t);
  __syncthreads();

  int e = blockIdx.x * 256 + t;
  if (e >= E) return;
  int src = ei[e];
  int dst = ei[E + e];
  int2 a = *(const int2*)&ea[2 * e];
  int pos = offs[dst] + sPre[dst >> 10] + rank[e];
  recs[pos] = (u32)src | ((u32)(a.x * 6 + a.y) << 26);
}

// =====================================================================
// k_gather: one wave per node, 2 edges concurrently (32 lanes/edge,
// dwordx2/lane), pair-loop unrolled x8 => 16 edge-loads in flight/wave.
// emb table staged as f32 (precomputed in k_setup) -> no per-block
// recompute, no per-edge emb unpack.
// =====================================================================
__global__ __launch_bounds__(256) void k_gather(
    const int* __restrict__ offs, const int* __restrict__ bsum, int nb,
    const u32* __restrict__ recs, const float* __restrict__ embF,
    const u32* __restrict__ xenc32, u32* __restrict__ aggb, int N, int E)
{
  __shared__ float sE[36 * 128];   // 18.4 KB, f32 combined emb
  __shared__ int sPre[256];

  const int t = threadIdx.x;
  for (int i = t; i < 1152; i += 256)         // 36*128 floats = 1152 float4
    ((float4*)sE)[i] = ((const float4*)embF)[i];
  if (t < 64) wave_scan_bsum(bsum, nb, sPre, t);
  __syncthreads();

  const int v = blockIdx.x * 4 + (t >> 6);
  if (v >= N) return;
  const int lane = t & 63, g = lane >> 5, sub = lane & 31;
  const u32 M = 0x3ffffffu;

  float a[4];
  #pragma unroll
  for (int j = 0; j < 4; j++) a[j] = 0.f;

  if (g == 0) {                           // self-loop (combo 5*6+0=30)
    uint2 xq = *(const uint2*)&xenc32[(size_t)v * 64 + sub * 2];
    float4 eq = *(const float4*)&sE[30 * 128 + sub * 4];
    accf(a, xq, eq);
  }

  const int beg = offs[v] + sPre[v >> 10];
  const int end = (v == N - 1) ? E : (offs[v + 1] + sPre[(v + 1) >> 10]);

  for (int base = beg; base < end; base += 64) {
    u32 rv = 0;
    if (base + lane < end) rv = recs[base + lane];
    const int cnt = min(64, end - base);
    const int npair = cnt >> 1;
    int jj = 0;
    for (; jj + 8 <= npair; jj += 8) {
      u32 r0 = __shfl(rv, (jj + 0) * 2 + g);
      u32 r1 = __shfl(rv, (jj + 1) * 2 + g);
      u32 r2 = __shfl(rv, (jj + 2) * 2 + g);
      u32 r3 = __shfl(rv, (jj + 3) * 2 + g);
      u32 r4 = __shfl(rv, (jj + 4) * 2 + g);
      u32 r5 = __shfl(rv, (jj + 5) * 2 + g);
      u32 r6 = __shfl(rv, (jj + 6) * 2 + g);
      u32 r7 = __shfl(rv, (jj + 7) * 2 + g);
      uint2 x0 = *(const uint2*)&xenc32[(size_t)(r0 & M) * 64 + sub * 2];
      uint2 x1 = *(const uint2*)&xenc32[(size_t)(r1 & M) * 64 + sub * 2];
      uint2 x2 = *(const uint2*)&xenc32[(size_t)(r2 & M) * 64 + sub * 2];
      uint2 x3 = *(const uint2*)&xenc32[(size_t)(r3 & M) * 64 + sub * 2];
      uint2 x4 = *(const uint2*)&xenc32[(size_t)(r4 & M) * 64 + sub * 2];
      uint2 x5 = *(const uint2*)&xenc32[(size_t)(r5 & M) * 64 + sub * 2];
      uint2 x6 = *(const uint2*)&xenc32[(size_t)(r6 & M) * 64 + sub * 2];
      uint2 x7 = *(const uint2*)&xenc32[(size_t)(r7 & M) * 64 + sub * 2];
      float4 e0 = *(const float4*)&sE[(r0 >> 26) * 128 + sub * 4];
      float4 e1 = *(const float4*)&sE[(r1 >> 26) * 128 + sub * 4];
      float4 e2 = *(const float4*)&sE[(r2 >> 26) * 128 + sub * 4];
      float4 e3 = *(const float4*)&sE[(r3 >> 26) * 128 + sub * 4];
      float4 e4 = *(const float4*)&sE[(r4 >> 26) * 128 + sub * 4];
      float4 e5 = *(const float4*)&sE[(r5 >> 26) * 128 + sub * 4];
      float4 e6 = *(const float4*)&sE[(r6 >> 26) * 128 + sub * 4];
      float4 e7 = *(const float4*)&sE[(r7 >> 26) * 128 + sub * 4];
      accf(a, x0, e0); accf(a, x1, e1); accf(a, x2, e2); accf(a, x3, e3);
      accf(a, x4, e4); accf(a, x5, e5); accf(a, x6, e6); accf(a, x7, e7);
    }
    for (; jj < npair; jj++) {
      u32 r = __shfl(rv, jj * 2 + g);
      uint2 xq = *(const uint2*)&xenc32[(size_t)(r & M) * 64 + sub * 2];
      float4 eq = *(const float4*)&sE[(r >> 26) * 128 + sub * 4];
      accf(a, xq, eq);
    }
    if (cnt & 1) {                        // odd tail: group 0 handles it
      u32 r = __shfl(rv, cnt - 1);
      if (g == 0) {
        uint2 xq = *(const uint2*)&xenc32[(size_t)(r & M) * 64 + sub * 2];
        float4 eq = *(const float4*)&sE[(r >> 26) * 128 + sub * 4];
        accf(a, xq, eq);
      }
    }
  }

  #pragma unroll
  for (int j = 0; j < 4; j++) a[j] += __shfl_xor(a[j], 32);

  if (g == 0) {
    uint2 o;
    o.x = pk2(a[0], a[1]);
    o.y = pk2(a[2], a[3]);
    *(uint2*)&aggb[(size_t)v * 64 + sub * 2] = o;
  }
}

// =====================================================================
// k_mlp (fused): out = silu(agg @ W1 + b1) @ W2 + b2
// 128 rows/block. W1-half and W2-half share ONE LDS buffer (re-staged
// after GEMM1) -> ~71 KB LDS -> 2 blocks/CU.
// =====================================================================
__global__ __launch_bounds__(256) void k_mlp(
    const u16* __restrict__ aggb, const u16* __restrict__ W1T,
    const float* __restrict__ b1, const u16* __restrict__ W2T,
    const float* __restrict__ b2, float* __restrict__ out, int N)
{
  const int SK = 136;
  __shared__ u16 sW[128 * SK];      // 34 KB: W1 n-half, then W2 k-half
  __shared__ u16 sH[128 * SK];      // 34 KB: h tile (128 rows x 128 cols)
  __shared__ float sB1[256];
  __shared__ float sB2[128];

  const int t = threadIdx.x;
  const int lane = t & 63, wave = t >> 6, quad = lane >> 4, l16 = lane & 15;
  const int m0 = blockIdx.x * 128 + wave * 32;

  if (t < 128) sB2[t] = b2[t];
  sB1[t] = b1[t];

  // A fragments (aggb rows) loaded once, reused across both halves
  union { uint4 q; short8 s; } a[2][4];
  #pragma unroll
  for (int mr = 0; mr < 2; mr++) {
    int row = min(m0 + mr * 16 + l16, N - 1);
    #pragma unroll
    for (int ks = 0; ks < 4; ks++)
      a[mr][ks].q = *(const uint4*)&aggb[(size_t)row * 128 + ks * 32 + quad * 8];
  }

  f32x4 acc2[2][8];
  #pragma unroll
  for (int mr = 0; mr < 2; mr++)
    #pragma unroll
    for (int nt = 0; nt < 8; nt++) acc2[mr][nt] = (f32x4){0.f, 0.f, 0.f, 0.f};

  for (int half = 0; half < 2; half++) {
    // stage W1 n-half
    #pragma unroll
    for (int j = 0; j < 8; j++) {
      int i = t + 256 * j;
      int n = i >> 4, k8 = i & 15;
      *(uint4*)&sW[n * SK + k8 * 8] =
          *(const uint4*)&W1T[(size_t)(half * 128 + n) * 128 + k8 * 8];
    }
    __syncthreads();

    // GEMM1: h_half = agg @ W1half
    f32x4 acc1[2][8];
    #pragma unroll
    for (int mr = 0; mr < 2; mr++)
      #pragma unroll
      for (int nt = 0; nt < 8; nt++) acc1[mr][nt] = (f32x4){0.f, 0.f, 0.f, 0.f};

    #pragma unroll
    for (int ks = 0; ks < 4; ks++) {
      const int k0 = ks * 32 + quad * 8;
      #pragma unroll
      for (int nt = 0; nt < 8; nt++) {
        short8 b = *(const short8*)&sW[(nt * 16 + l16) * SK + k0];
        acc1[0][nt] = __builtin_amdgcn_mfma_f32_16x16x32_bf16(a[0][ks].s, b, acc1[0][nt], 0, 0, 0);
        acc1[1][nt] = __builtin_amdgcn_mfma_f32_16x16x32_bf16(a[1][ks].s, b, acc1[1][nt], 0, 0, 0);
      }
    }

    // silu + C-layout -> A-layout via LDS tile (wave-local rows)
    #pragma unroll
    for (int mr = 0; mr < 2; mr++)
      #pragma unroll
      for (int nt = 0; nt < 8; nt++) {
        int col = nt * 16 + l16;
        float bias = sB1[half * 128 + col];
        #pragma unroll
        for (int r = 0; r < 4; r++) {
          float z = acc1[mr][nt][r] + bias;
          float s = z / (1.f + __expf(-z));
          sH[(wave * 32 + mr * 16 + quad * 4 + r) * SK + col] = f2b(s);
        }
      }
    __syncthreads();          // all waves done reading sW (GEMM1)

    // re-stage sW with W2 k-half
    #pragma unroll
    for (int j = 0; j < 8; j++) {
      int i = t + 256 * j;
      int n = i >> 4, k8 = i & 15;
      *(uint4*)&sW[n * SK + k8 * 8] =
          *(const uint4*)&W2T[(size_t)n * 256 + half * 128 + k8 * 8];
    }
    __syncthreads();

    // GEMM2: out_acc += h_half @ W2_khalf
    #pragma unroll
    for (int ks = 0; ks < 4; ks++) {
      const int k0 = ks * 32 + quad * 8;
      union { uint4 q; short8 s; } ah[2];
      #pragma unroll
      for (int mr = 0; mr < 2; mr++)
        ah[mr].q = *(const uint4*)&sH[(wave * 32 + mr * 16 + l16) * SK + k0];
      #pragma unroll
      for (int nt = 0; nt < 8; nt++) {
        short8 b = *(const short8*)&sW[(nt * 16 + l16) * SK + k0];
        acc2[0][nt] = __builtin_amdgcn_mfma_f32_16x16x32_bf16(ah[0].s, b, acc2[0][nt], 0, 0, 0);
        acc2[1][nt] = __builtin_amdgcn_mfma_f32_16x16x32_bf16(ah[1].s, b, acc2[1][nt], 0, 0, 0);
      }
    }
    __syncthreads();          // all waves done reading sW before next half
  }

  #pragma unroll
  for (int mr = 0; mr < 2; mr++)
    #pragma unroll
    for (int nt = 0; nt < 8; nt++) {
      int col = nt * 16 + l16;
      float bias = sB2[col];
      #pragma unroll
      for (int r = 0; r < 4; r++) {
        int row = m0 + mr * 16 + quad * 4 + r;
        if (row < N) out[(size_t)row * 128 + col] = acc2[mr][nt][r] + bias;
      }
    }
}

// =====================================================================
extern "C" void kernel_launch(void* const* d_in, const int* in_sizes, int n_in,
                              void* d_out, int out_size, void* d_ws, size_t ws_size,
                              hipStream_t stream) {
  const float* x    = (const float*)d_in[0];
  const int*   ei   = (const int*)d_in[1];
  const int*   ea   = (const int*)d_in[2];
  const float* pa   = (const float*)d_in[3];
  const float* Wenc = (const float*)d_in[4];
  const float* e1   = (const float*)d_in[5];
  const float* e2   = (const float*)d_in[6];
  const float* W1   = (const float*)d_in[7];
  const float* b1   = (const float*)d_in[8];
  const float* W2   = (const float*)d_in[9];
  const float* b2   = (const float*)d_in[10];
  float* out = (float*)d_out;

  const int N = in_sizes[0] / 128;
  const int E = in_sizes[1] / 2;

  char* ws = (char*)d_ws;
  size_t off = 0;
  auto alloc = [&](size_t bytes) {
    void* p = ws + off;
    off = (off + bytes + 255) & ~(size_t)255;
    return p;
  };
  u16*   xenc   = (u16*)  alloc((size_t)N * 128 * 2);
  u32*   aggb   = (u32*)  alloc((size_t)N * 64 * 4);   // bf16 agg, packed
  int*   cnt    = (int*)  alloc((size_t)N * 4);
  int*   offs   = (int*)  alloc((size_t)(N + 1) * 4);
  int*   rank   = (int*)  alloc((size_t)E * 4);
  int*   bsum   = (int*)  alloc(256 * 4);
  u32*   recs   = (u32*)  alloc((size_t)E * 4);
  u16*   WencT  = (u16*)  alloc(128 * 128 * 2);
  u16*   W1T    = (u16*)  alloc(256 * 128 * 2);
  u16*   W2T    = (u16*)  alloc(128 * 256 * 2);
  float* embF   = (float*)alloc(36 * 128 * 4);

  const int encBlocks   = (N + 127) / 128;
  const int edgeBlocks  = (E + 255) / 256;
  const int setupBlocks = (81920 + 4608 + N + 255) / 256;
  const int nb          = (N + 1023) / 1024;

  k_setup<<<setupBlocks, 256, 0, stream>>>(Wenc, W1, W2, e1, e2,
                                           WencT, W1T, W2T, embF, cnt, N);
  k_enc_count<<<encBlocks + edgeBlocks, 256, 0, stream>>>(
      x, pa, WencT, xenc, N, ei, cnt, rank, E, encBlocks);
  k_scan_block<<<nb, 256, 0, stream>>>(cnt, offs, bsum, N);
  k_fill<<<edgeBlocks, 256, 0, stream>>>(ei, ea, offs, rank, bsum, nb, recs, E);
  k_gather<<<(N + 3) / 4, 256, 0, stream>>>(
      offs, bsum, nb, recs, embF, (const u32*)xenc, aggb, N, E);
  k_mlp<<<encBlocks, 256, 0, stream>>>(
      (const u16*)aggb, W1T, b1, W2T, b2, out, N);
}

// Round 2
// 233.020 us; speedup vs baseline: 1.0205x; 1.0205x over previous
//
#include <hip/hip_runtime.h>

typedef unsigned short u16;
typedef unsigned int   u32;
typedef __attribute__((ext_vector_type(8))) short short8;   // 8 bf16 (4 VGPRs)
typedef __attribute__((ext_vector_type(4))) float f32x4;    // MFMA C/D

// ---- bf16 helpers (bf16 = top 16 bits of fp32; half-up rounding) ----
__device__ __forceinline__ float bl(u32 u){ union{u32 i; float f;} c; c.i = u << 16; return c.f; }
__device__ __forceinline__ float bh(u32 u){ union{u32 i; float f;} c; c.i = u & 0xffff0000u; return c.f; }
__device__ __forceinline__ u16 f2b(float f){
  union{float f; u32 i;} c; c.f = f;
  return (u16)((c.i + 0x8000u) >> 16);
}
__device__ __forceinline__ u32 pk2(float a, float b){
  union{float f; u32 i;} x, y; x.f = a; y.f = b;
  return ((x.i + 0x8000u) >> 16) | ((y.i + 0x8000u) & 0xffff0000u);
}

// one-wave exclusive scan of bsum[0..nb) into sPre (call with t < 64)
__device__ __forceinline__ void wave_scan_bsum(
    const int* __restrict__ bsum, int nb, int* __restrict__ sPre, int t)
{
  int carry = 0;
  for (int c0 = 0; c0 < nb; c0 += 64) {
    int idx = c0 + t;
    int b = (idx < nb) ? bsum[idx] : 0;
    int v = b;
    #pragma unroll
    for (int d = 1; d < 64; d <<= 1) {
      int u = __shfl_up(v, d);
      if (t >= d) v += u;
    }
    if (idx < nb) sPre[idx] = carry + v - b;   // exclusive
    carry += __shfl(v, 63);
  }
}

// =====================================================================
// k_setup: transpose weights to bf16 n-major WT[n][k], build combined
// f32 emb table embF[36][128], zero cnt.
// =====================================================================
__global__ __launch_bounds__(256) void k_setup(
    const float* __restrict__ Wenc, const float* __restrict__ W1,
    const float* __restrict__ W2, const float* __restrict__ e1,
    const float* __restrict__ e2, u16* __restrict__ WencT,
    u16* __restrict__ W1T, u16* __restrict__ W2T,
    float* __restrict__ embF, int* __restrict__ cnt, int N)
{
  int i = blockIdx.x * 256 + threadIdx.x;
  if (i < 16384) {                        // WencT: [128 n][128 k]
    int n = i >> 7, k = i & 127;
    WencT[i] = f2b(Wenc[k * 128 + n]);
  } else if (i < 49152) {                 // W1T: [256 n][128 k]
    int j = i - 16384;
    int n = j >> 7, k = j & 127;
    W1T[j] = f2b(W1[k * 256 + n]);
  } else if (i < 81920) {                 // W2T: [128 n][256 k]
    int j = i - 49152;
    int n = j >> 8, k = j & 255;
    W2T[j] = f2b(W2[k * 128 + n]);
  } else if (i < 81920 + 4608) {          // embF: [36 combo][128 k] f32
    int j = i - 81920;
    int comb = j >> 7, k = j & 127;
    int c1 = comb / 6, c2 = comb - c1 * 6;
    embF[j] = e1[c1 * 128 + k] + e2[c2 * 128 + k];
  } else {
    int j = i - 81920 - 4608;
    if (j < N) cnt[j] = 0;
  }
}

// =====================================================================
// k_enc_count: blocks [0, encBlocks) -> xencQ = bf16(PReLU(x) @ W_enc),
//              stored QUARTER-MAJOR: xencQ[q][node][32 cols]
//              blocks [encBlocks,..) -> degree histogram + per-edge rank
// =====================================================================
__global__ __launch_bounds__(256) void k_enc_count(
    const float* __restrict__ x, const float* __restrict__ pa,
    const u16* __restrict__ WT, u16* __restrict__ xencQ, int N,
    const int* __restrict__ ei, int* __restrict__ cnt,
    int* __restrict__ rank, int E, int encBlocks)
{
  if ((int)blockIdx.x >= encBlocks) {
    int e = ((int)blockIdx.x - encBlocks) * 256 + threadIdx.x;
    if (e < E) rank[e] = atomicAdd(&cnt[ei[E + e]], 1);
    return;
  }

  const int K = 128, SK = 136, NT = 8;
  __shared__ u16 sB[128 * SK];           // 34 KB

  const int t = threadIdx.x;
  #pragma unroll
  for (int j = 0; j < 8; j++) {
    int i = t + 256 * j;
    int n = i >> 4, k8 = i & 15;
    *(uint4*)&sB[n * SK + k8 * 8] = *(const uint4*)&WT[n * K + k8 * 8];
  }
  __syncthreads();

  const float slope = pa[0];
  const int lane = t & 63, wave = t >> 6, quad = lane >> 4, l16 = lane & 15;
  const int m0 = blockIdx.x * 128 + wave * 32;
  if (m0 >= N) return;

  f32x4 acc[2][NT];
  #pragma unroll
  for (int mr = 0; mr < 2; mr++)
    #pragma unroll
    for (int nt = 0; nt < NT; nt++) acc[mr][nt] = (f32x4){0.f, 0.f, 0.f, 0.f};

  #pragma unroll
  for (int ks = 0; ks < 4; ks++) {
    const int k0 = ks * 32 + quad * 8;
    union { u32 u[4]; short8 s; } a[2];
    #pragma unroll
    for (int mr = 0; mr < 2; mr++) {
      int row = m0 + mr * 16 + l16; row = min(row, N - 1);
      const float4* ap = (const float4*)&x[(size_t)row * 128 + k0];
      float4 f0 = ap[0], f1 = ap[1];
      float v0 = f0.x > 0.f ? f0.x : slope * f0.x;
      float v1 = f0.y > 0.f ? f0.y : slope * f0.y;
      float v2 = f0.z > 0.f ? f0.z : slope * f0.z;
      float v3 = f0.w > 0.f ? f0.w : slope * f0.w;
      float v4 = f1.x > 0.f ? f1.x : slope * f1.x;
      float v5 = f1.y > 0.f ? f1.y : slope * f1.y;
      float v6 = f1.z > 0.f ? f1.z : slope * f1.z;
      float v7 = f1.w > 0.f ? f1.w : slope * f1.w;
      a[mr].u[0] = pk2(v0, v1); a[mr].u[1] = pk2(v2, v3);
      a[mr].u[2] = pk2(v4, v5); a[mr].u[3] = pk2(v6, v7);
    }
    #pragma unroll
    for (int nt = 0; nt < NT; nt++) {
      short8 b = *(const short8*)&sB[(nt * 16 + l16) * SK + k0];
      acc[0][nt] = __builtin_amdgcn_mfma_f32_16x16x32_bf16(a[0].s, b, acc[0][nt], 0, 0, 0);
      acc[1][nt] = __builtin_amdgcn_mfma_f32_16x16x32_bf16(a[1].s, b, acc[1][nt], 0, 0, 0);
    }
  }

  #pragma unroll
  for (int mr = 0; mr < 2; mr++)
    #pragma unroll
    for (int nt = 0; nt < NT; nt++) {
      int col = nt * 16 + l16;
      int q = col >> 5, cq = col & 31;
      #pragma unroll
      for (int r = 0; r < 4; r++) {
        int row = m0 + mr * 16 + quad * 4 + r;
        if (row < N)
          xencQ[((size_t)q * N + row) * 32 + cq] = f2b(acc[mr][nt][r]);
      }
    }
}

// =====================================================================
// k_scan_block: per-1024-chunk exclusive scan of cnt -> offs, + bsum.
// =====================================================================
__global__ __launch_bounds__(256) void k_scan_block(
    const int* __restrict__ cnt, int* __restrict__ offs,
    int* __restrict__ bsum, int n)
{
  __shared__ int sS[256];
  const int b = blockIdx.x, t = threadIdx.x;
  const int i0 = b * 1024 + t * 4;
  int4 v = make_int4(0, 0, 0, 0);
  if (i0 + 3 < n) v = *(const int4*)&cnt[i0];
  else {
    if (i0     < n) v.x = cnt[i0];
    if (i0 + 1 < n) v.y = cnt[i0 + 1];
    if (i0 + 2 < n) v.z = cnt[i0 + 2];
  }
  int s = v.x + v.y + v.z + v.w;
  sS[t] = s;
  __syncthreads();
  for (int d = 1; d < 256; d <<= 1) {
    int val = (t >= d) ? sS[t - d] : 0;
    __syncthreads();
    sS[t] += val;
    __syncthreads();
  }
  int ex = sS[t] - s;
  if (t == 255) bsum[b] = sS[t];
  int o0 = ex, o1 = o0 + v.x, o2 = o1 + v.y, o3 = o2 + v.z;
  if (i0     < n) offs[i0]     = o0;
  if (i0 + 1 < n) offs[i0 + 1] = o1;
  if (i0 + 2 < n) offs[i0 + 2] = o2;
  if (i0 + 3 < n) offs[i0 + 3] = o3;
}

// =====================================================================
// k_fill: atomic-free scatter of packed edge records (uses rank).
// rec = src | (a1*6+a2) << 26.  Adds bsum prefix inline.
// =====================================================================
__global__ __launch_bounds__(256) void k_fill(
    const int* __restrict__ ei, const int* __restrict__ ea,
    const int* __restrict__ offs, const int* __restrict__ rank,
    const int* __restrict__ bsum, int nb,
    u32* __restrict__ recs, int E)
{
  __shared__ int sPre[256];
  const int t = threadIdx.x;
  if (t < 64) wave_scan_bsum(bsum, nb, sPre, t);
  __syncthreads();

  int e = blockIdx.x * 256 + t;
  if (e >= E) return;
  int src = ei[e];
  int dst = ei[E + e];
  int2 a = *(const int2*)&ea[2 * e];
  int pos = offs[dst] + sPre[dst >> 10] + rank[e];
  recs[pos] = (u32)src | ((u32)(a.x * 6 + a.y) << 26);
}

// =====================================================================
// k_gather (quartered): whole grid co-resident (1563 blocks); every
// block loops q=0..3 so all CUs gather from the SAME 3.2 MB xenc
// quarter at a time -> per-XCD-L2 resident -> L2 hits instead of
// L2 misses (the r1-measured per-CU outstanding-miss ceiling).
// 8 lanes/edge (64 B quarter-row); each 8-lane group owns one node
// (no cross-group reduce); 8 gathers in flight per batch.
// =====================================================================
__global__ __launch_bounds__(256) void k_gather(
    const int* __restrict__ offs, const int* __restrict__ bsum, int nb,
    const u32* __restrict__ recs, const float* __restrict__ embF,
    const u32* __restrict__ xencQ, u32* __restrict__ aggbQ, int N, int E)
{
  const int ES = 36;                 // emb row stride (floats), 16B-aligned
  __shared__ float sE4[4 * 36 * ES]; // 20.7 KB quarter-major emb
  __shared__ int sPre[256];

  const int t = threadIdx.x;
  for (int i = t; i < 4 * 36 * 8; i += 256) {
    int q = i / (36 * 8);
    int r = i - q * 36 * 8;
    int c = r >> 3, s4 = r & 7;
    float4 v = *(const float4*)&embF[c * 128 + q * 32 + s4 * 4];
    *(float4*)&sE4[(q * 36 + c) * ES + s4 * 4] = v;
  }
  if (t < 64) wave_scan_bsum(bsum, nb, sPre, t);
  __syncthreads();

  const int lane = t & 63, wave = t >> 6;
  const int g = lane >> 3, sub = lane & 7;
  const int v = blockIdx.x * 32 + wave * 8 + g;
  const bool vok = v < N;
  const int vc = vok ? v : N - 1;
  const int beg = offs[vc] + sPre[vc >> 10];
  const int end = (vc == N - 1) ? E : (offs[vc + 1] + sPre[(vc + 1) >> 10]);
  const int deg = vok ? end - beg : 0;
  const u32 M = 0x3ffffffu;

  #pragma unroll
  for (int q = 0; q < 4; q++) {
    const u32* xq = xencQ + (size_t)q * N * 16;   // u32 units: 16/row
    const float* sEq = &sE4[q * 36 * ES];

    // self-loop (combo 5*6+0 = 30)
    uint2 xs = *(const uint2*)&xq[(size_t)vc * 16 + sub * 2];
    float4 es = *(const float4*)&sEq[30 * ES + sub * 4];
    float a0 = bl(xs.x) + es.x, a1 = bh(xs.x) + es.y;
    float a2 = bl(xs.y) + es.z, a3 = bh(xs.y) + es.w;

    for (int j0 = 0; j0 < deg; j0 += 8) {
      int idx = beg + j0 + sub;
      u32 rv = recs[min(idx, end - 1)];
      #pragma unroll
      for (int k = 0; k < 8; k++) {
        u32 r = __shfl(rv, (lane & 56) + k);  // intra-group broadcast
        if (j0 + k < deg) {                    // uniform within group
          uint2 xr = *(const uint2*)&xq[(size_t)(r & M) * 16 + sub * 2];
          float4 er = *(const float4*)&sEq[(r >> 26) * ES + sub * 4];
          a0 += bl(xr.x) + er.x;  a1 += bh(xr.x) + er.y;
          a2 += bl(xr.y) + er.z;  a3 += bh(xr.y) + er.w;
        }
      }
    }

    if (vok) {
      uint2 o;
      o.x = pk2(a0, a1);
      o.y = pk2(a2, a3);
      *(uint2*)&aggbQ[((size_t)q * N + vc) * 16 + sub * 2] = o;
    }
  }
}

// =====================================================================
// k_mlp (fused): out = silu(agg @ W1 + b1) @ W2 + b2
// A-fragments read from quarter-major aggbQ (ks == quarter).
// =====================================================================
__global__ __launch_bounds__(256) void k_mlp(
    const u16* __restrict__ aggbQ, const u16* __restrict__ W1T,
    const float* __restrict__ b1, const u16* __restrict__ W2T,
    const float* __restrict__ b2, float* __restrict__ out, int N)
{
  const int SK = 136;
  __shared__ u16 sW[128 * SK];      // 34 KB: W1 n-half, then W2 k-half
  __shared__ u16 sH[128 * SK];      // 34 KB: h tile (128 rows x 128 cols)
  __shared__ float sB1[256];
  __shared__ float sB2[128];

  const int t = threadIdx.x;
  const int lane = t & 63, wave = t >> 6, quad = lane >> 4, l16 = lane & 15;
  const int m0 = blockIdx.x * 128 + wave * 32;

  if (t < 128) sB2[t] = b2[t];
  sB1[t] = b1[t];

  // A fragments (aggb rows) loaded once, reused across both halves
  union { uint4 q; short8 s; } a[2][4];
  #pragma unroll
  for (int mr = 0; mr < 2; mr++) {
    int row = min(m0 + mr * 16 + l16, N - 1);
    #pragma unroll
    for (int ks = 0; ks < 4; ks++)
      a[mr][ks].q = *(const uint4*)&aggbQ[((size_t)ks * N + row) * 32 + quad * 8];
  }

  f32x4 acc2[2][8];
  #pragma unroll
  for (int mr = 0; mr < 2; mr++)
    #pragma unroll
    for (int nt = 0; nt < 8; nt++) acc2[mr][nt] = (f32x4){0.f, 0.f, 0.f, 0.f};

  for (int half = 0; half < 2; half++) {
    // stage W1 n-half
    #pragma unroll
    for (int j = 0; j < 8; j++) {
      int i = t + 256 * j;
      int n = i >> 4, k8 = i & 15;
      *(uint4*)&sW[n * SK + k8 * 8] =
          *(const uint4*)&W1T[(size_t)(half * 128 + n) * 128 + k8 * 8];
    }
    __syncthreads();

    // GEMM1: h_half = agg @ W1half
    f32x4 acc1[2][8];
    #pragma unroll
    for (int mr = 0; mr < 2; mr++)
      #pragma unroll
      for (int nt = 0; nt < 8; nt++) acc1[mr][nt] = (f32x4){0.f, 0.f, 0.f, 0.f};

    #pragma unroll
    for (int ks = 0; ks < 4; ks++) {
      const int k0 = ks * 32 + quad * 8;
      #pragma unroll
      for (int nt = 0; nt < 8; nt++) {
        short8 b = *(const short8*)&sW[(nt * 16 + l16) * SK + k0];
        acc1[0][nt] = __builtin_amdgcn_mfma_f32_16x16x32_bf16(a[0][ks].s, b, acc1[0][nt], 0, 0, 0);
        acc1[1][nt] = __builtin_amdgcn_mfma_f32_16x16x32_bf16(a[1][ks].s, b, acc1[1][nt], 0, 0, 0);
      }
    }

    // silu + C-layout -> A-layout via LDS tile (wave-local rows)
    #pragma unroll
    for (int mr = 0; mr < 2; mr++)
      #pragma unroll
      for (int nt = 0; nt < 8; nt++) {
        int col = nt * 16 + l16;
        float bias = sB1[half * 128 + col];
        #pragma unroll
        for (int r = 0; r < 4; r++) {
          float z = acc1[mr][nt][r] + bias;
          float s = z / (1.f + __expf(-z));
          sH[(wave * 32 + mr * 16 + quad * 4 + r) * SK + col] = f2b(s);
        }
      }
    __syncthreads();          // all waves done reading sW (GEMM1)

    // re-stage sW with W2 k-half
    #pragma unroll
    for (int j = 0; j < 8; j++) {
      int i = t + 256 * j;
      int n = i >> 4, k8 = i & 15;
      *(uint4*)&sW[n * SK + k8 * 8] =
          *(const uint4*)&W2T[(size_t)n * 256 + half * 128 + k8 * 8];
    }
    __syncthreads();

    // GEMM2: out_acc += h_half @ W2_khalf
    #pragma unroll
    for (int ks = 0; ks < 4; ks++) {
      const int k0 = ks * 32 + quad * 8;
      union { uint4 q; short8 s; } ah[2];
      #pragma unroll
      for (int mr = 0; mr < 2; mr++)
        ah[mr].q = *(const uint4*)&sH[(wave * 32 + mr * 16 + l16) * SK + k0];
      #pragma unroll
      for (int nt = 0; nt < 8; nt++) {
        short8 b = *(const short8*)&sW[(nt * 16 + l16) * SK + k0];
        acc2[0][nt] = __builtin_amdgcn_mfma_f32_16x16x32_bf16(ah[0].s, b, acc2[0][nt], 0, 0, 0);
        acc2[1][nt] = __builtin_amdgcn_mfma_f32_16x16x32_bf16(ah[1].s, b, acc2[1][nt], 0, 0, 0);
      }
    }
    __syncthreads();          // all waves done reading sW before next half
  }

  #pragma unroll
  for (int mr = 0; mr < 2; mr++)
    #pragma unroll
    for (int nt = 0; nt < 8; nt++) {
      int col = nt * 16 + l16;
      float bias = sB2[col];
      #pragma unroll
      for (int r = 0; r < 4; r++) {
        int row = m0 + mr * 16 + quad * 4 + r;
        if (row < N) out[(size_t)row * 128 + col] = acc2[mr][nt][r] + bias;
      }
    }
}

// =====================================================================
extern "C" void kernel_launch(void* const* d_in, const int* in_sizes, int n_in,
                              void* d_out, int out_size, void* d_ws, size_t ws_size,
                              hipStream_t stream) {
  const float* x    = (const float*)d_in[0];
  const int*   ei   = (const int*)d_in[1];
  const int*   ea   = (const int*)d_in[2];
  const float* pa   = (const float*)d_in[3];
  const float* Wenc = (const float*)d_in[4];
  const float* e1   = (const float*)d_in[5];
  const float* e2   = (const float*)d_in[6];
  const float* W1   = (const float*)d_in[7];
  const float* b1   = (const float*)d_in[8];
  const float* W2   = (const float*)d_in[9];
  const float* b2   = (const float*)d_in[10];
  float* out = (float*)d_out;

  const int N = in_sizes[0] / 128;
  const int E = in_sizes[1] / 2;

  char* ws = (char*)d_ws;
  size_t off = 0;
  auto alloc = [&](size_t bytes) {
    void* p = ws + off;
    off = (off + bytes + 255) & ~(size_t)255;
    return p;
  };
  u16*   xencQ  = (u16*)  alloc((size_t)N * 128 * 2);  // quarter-major
  u32*   aggbQ  = (u32*)  alloc((size_t)N * 64 * 4);   // quarter-major bf16
  int*   cnt    = (int*)  alloc((size_t)N * 4);
  int*   offs   = (int*)  alloc((size_t)(N + 1) * 4);
  int*   rank   = (int*)  alloc((size_t)E * 4);
  int*   bsum   = (int*)  alloc(256 * 4);
  u32*   recs   = (u32*)  alloc((size_t)E * 4);
  u16*   WencT  = (u16*)  alloc(128 * 128 * 2);
  u16*   W1T    = (u16*)  alloc(256 * 128 * 2);
  u16*   W2T    = (u16*)  alloc(128 * 256 * 2);
  float* embF   = (float*)alloc(36 * 128 * 4);

  const int encBlocks   = (N + 127) / 128;
  const int edgeBlocks  = (E + 255) / 256;
  const int setupBlocks = (81920 + 4608 + N + 255) / 256;
  const int nb          = (N + 1023) / 1024;
  const int gatherBlocks = (N + 31) / 32;

  k_setup<<<setupBlocks, 256, 0, stream>>>(Wenc, W1, W2, e1, e2,
                                           WencT, W1T, W2T, embF, cnt, N);
  k_enc_count<<<encBlocks + edgeBlocks, 256, 0, stream>>>(
      x, pa, WencT, xencQ, N, ei, cnt, rank, E, encBlocks);
  k_scan_block<<<nb, 256, 0, stream>>>(cnt, offs, bsum, N);
  k_fill<<<edgeBlocks, 256, 0, stream>>>(ei, ea, offs, rank, bsum, nb, recs, E);
  k_gather<<<gatherBlocks, 256, 0, stream>>>(
      offs, bsum, nb, recs, embF, (const u32*)xencQ, aggbQ, N, E);
  k_mlp<<<encBlocks, 256, 0, stream>>>(
      (const u16*)aggbQ, W1T, b1, W2T, b2, out, N);
}

// Round 3
// 223.955 us; speedup vs baseline: 1.0618x; 1.0405x over previous
//
#include <hip/hip_runtime.h>

typedef unsigned short u16;
typedef unsigned int   u32;
typedef __attribute__((ext_vector_type(8))) short short8;   // 8 bf16 (4 VGPRs)
typedef __attribute__((ext_vector_type(4))) float f32x4;    // MFMA C/D

// ---- bf16 helpers (bf16 = top 16 bits of fp32; half-up rounding) ----
__device__ __forceinline__ float bl(u32 u){ union{u32 i; float f;} c; c.i = u << 16; return c.f; }
__device__ __forceinline__ float bh(u32 u){ union{u32 i; float f;} c; c.i = u & 0xffff0000u; return c.f; }
__device__ __forceinline__ u16 f2b(float f){
  union{float f; u32 i;} c; c.f = f;
  return (u16)((c.i + 0x8000u) >> 16);
}
__device__ __forceinline__ u32 pk2(float a, float b){
  union{float f; u32 i;} x, y; x.f = a; y.f = b;
  return ((x.i + 0x8000u) >> 16) | ((y.i + 0x8000u) & 0xffff0000u);
}

// one-wave exclusive scan of bsum[0..nb) into sPre (call with t < 64)
__device__ __forceinline__ void wave_scan_bsum(
    const int* __restrict__ bsum, int nb, int* __restrict__ sPre, int t)
{
  int carry = 0;
  for (int c0 = 0; c0 < nb; c0 += 64) {
    int idx = c0 + t;
    int b = (idx < nb) ? bsum[idx] : 0;
    int v = b;
    #pragma unroll
    for (int d = 1; d < 64; d <<= 1) {
      int u = __shfl_up(v, d);
      if (t >= d) v += u;
    }
    if (idx < nb) sPre[idx] = carry + v - b;   // exclusive
    carry += __shfl(v, 63);
  }
}

// =====================================================================
// k_enc_count: blocks [0, encBlocks) -> xencQ = bf16(PReLU(x) @ W_enc),
//              stored QUARTER-MAJOR: xencQ[q][node][32 cols].
//              Wenc transposed f32->bf16 directly into LDS (no setup).
//              blocks [encBlocks,..) -> degree histogram + per-edge rank
// =====================================================================
__global__ __launch_bounds__(256) void k_enc_count(
    const float* __restrict__ x, const float* __restrict__ pa,
    const float* __restrict__ Wenc, u16* __restrict__ xencQ, int N,
    const int* __restrict__ ei, int* __restrict__ cnt,
    int* __restrict__ rank, int E, int encBlocks)
{
  if ((int)blockIdx.x >= encBlocks) {
    int e = ((int)blockIdx.x - encBlocks) * 256 + threadIdx.x;
    if (e < E) rank[e] = atomicAdd(&cnt[ei[E + e]], 1);
    return;
  }

  const int SK = 136, NT = 8;
  __shared__ u16 sB[128 * SK];           // 34 KB

  const int t = threadIdx.x;
  for (int j = 0; j < 64; j++) {         // Wenc is [k][n]; sB[n][k]
    int i = t + 256 * j;
    int k = i >> 7, n = i & 127;
    sB[n * SK + k] = f2b(Wenc[i]);
  }
  __syncthreads();

  const float slope = pa[0];
  const int lane = t & 63, wave = t >> 6, quad = lane >> 4, l16 = lane & 15;
  const int m0 = blockIdx.x * 128 + wave * 32;
  if (m0 >= N) return;

  f32x4 acc[2][NT];
  #pragma unroll
  for (int mr = 0; mr < 2; mr++)
    #pragma unroll
    for (int nt = 0; nt < NT; nt++) acc[mr][nt] = (f32x4){0.f, 0.f, 0.f, 0.f};

  #pragma unroll
  for (int ks = 0; ks < 4; ks++) {
    const int k0 = ks * 32 + quad * 8;
    union { u32 u[4]; short8 s; } a[2];
    #pragma unroll
    for (int mr = 0; mr < 2; mr++) {
      int row = m0 + mr * 16 + l16; row = min(row, N - 1);
      const float4* ap = (const float4*)&x[(size_t)row * 128 + k0];
      float4 f0 = ap[0], f1 = ap[1];
      float v0 = f0.x > 0.f ? f0.x : slope * f0.x;
      float v1 = f0.y > 0.f ? f0.y : slope * f0.y;
      float v2 = f0.z > 0.f ? f0.z : slope * f0.z;
      float v3 = f0.w > 0.f ? f0.w : slope * f0.w;
      float v4 = f1.x > 0.f ? f1.x : slope * f1.x;
      float v5 = f1.y > 0.f ? f1.y : slope * f1.y;
      float v6 = f1.z > 0.f ? f1.z : slope * f1.z;
      float v7 = f1.w > 0.f ? f1.w : slope * f1.w;
      a[mr].u[0] = pk2(v0, v1); a[mr].u[1] = pk2(v2, v3);
      a[mr].u[2] = pk2(v4, v5); a[mr].u[3] = pk2(v6, v7);
    }
    #pragma unroll
    for (int nt = 0; nt < NT; nt++) {
      short8 b = *(const short8*)&sB[(nt * 16 + l16) * SK + k0];
      acc[0][nt] = __builtin_amdgcn_mfma_f32_16x16x32_bf16(a[0].s, b, acc[0][nt], 0, 0, 0);
      acc[1][nt] = __builtin_amdgcn_mfma_f32_16x16x32_bf16(a[1].s, b, acc[1][nt], 0, 0, 0);
    }
  }

  #pragma unroll
  for (int mr = 0; mr < 2; mr++)
    #pragma unroll
    for (int nt = 0; nt < NT; nt++) {
      int col = nt * 16 + l16;
      int q = col >> 5, cq = col & 31;
      #pragma unroll
      for (int r = 0; r < 4; r++) {
        int row = m0 + mr * 16 + quad * 4 + r;
        if (row < N)
          xencQ[((size_t)q * N + row) * 32 + cq] = f2b(acc[mr][nt][r]);
      }
    }
}

// =====================================================================
// k_scanW: blocks [0,nb)  -> per-1024-chunk exclusive scan of cnt.
//          blocks [nb,..) -> W1T / W2T transpose + packed emb table.
// =====================================================================
__global__ __launch_bounds__(256) void k_scanW(
    const int* __restrict__ cnt, int* __restrict__ offs,
    int* __restrict__ bsum, int n, int nb,
    const float* __restrict__ W1, const float* __restrict__ W2,
    const float* __restrict__ e1, const float* __restrict__ e2,
    u16* __restrict__ W1T, u16* __restrict__ W2T, u32* __restrict__ embP)
{
  if ((int)blockIdx.x >= nb) {
    int i = ((int)blockIdx.x - nb) * 256 + threadIdx.x;   // [0, 67840)
    if (i < 32768) {                 // W1T: [256 n][128 k]
      int nn = i >> 7, k = i & 127;
      W1T[i] = f2b(W1[k * 256 + nn]);
    } else if (i < 65536) {          // W2T: [128 n][256 k]
      int j = i - 32768;
      int nn = j >> 8, k = j & 255;
      W2T[j] = f2b(W2[k * 128 + nn]);
    } else {                         // embP: [4 q][36 c][16 u32] packed bf16
      int j = i - 65536;             // [0, 2304)
      int q = j / 576, rem = j - q * 576;
      int c = rem >> 4, s = rem & 15;
      int c1 = c / 6, c2 = c - c1 * 6;
      int col = q * 32 + s * 2;
      embP[j] = pk2(e1[c1 * 128 + col]     + e2[c2 * 128 + col],
                    e1[c1 * 128 + col + 1] + e2[c2 * 128 + col + 1]);
    }
    return;
  }

  __shared__ int sS[256];
  const int b = blockIdx.x, t = threadIdx.x;
  const int i0 = b * 1024 + t * 4;
  int4 v = make_int4(0, 0, 0, 0);
  if (i0 + 3 < n) v = *(const int4*)&cnt[i0];
  else {
    if (i0     < n) v.x = cnt[i0];
    if (i0 + 1 < n) v.y = cnt[i0 + 1];
    if (i0 + 2 < n) v.z = cnt[i0 + 2];
  }
  int s = v.x + v.y + v.z + v.w;
  sS[t] = s;
  __syncthreads();
  for (int d = 1; d < 256; d <<= 1) {
    int val = (t >= d) ? sS[t - d] : 0;
    __syncthreads();
    sS[t] += val;
    __syncthreads();
  }
  int ex = sS[t] - s;
  if (t == 255) bsum[b] = sS[t];
  int o0 = ex, o1 = o0 + v.x, o2 = o1 + v.y, o3 = o2 + v.z;
  if (i0     < n) offs[i0]     = o0;
  if (i0 + 1 < n) offs[i0 + 1] = o1;
  if (i0 + 2 < n) offs[i0 + 2] = o2;
  if (i0 + 3 < n) offs[i0 + 3] = o3;
}

// =====================================================================
// k_fill: atomic-free scatter of packed edge records (uses rank).
// rec = src | (a1*6+a2) << 26.  Adds bsum prefix inline.
// =====================================================================
__global__ __launch_bounds__(256) void k_fill(
    const int* __restrict__ ei, const int* __restrict__ ea,
    const int* __restrict__ offs, const int* __restrict__ rank,
    const int* __restrict__ bsum, int nb,
    u32* __restrict__ recs, int E)
{
  __shared__ int sPre[256];
  const int t = threadIdx.x;
  if (t < 64) wave_scan_bsum(bsum, nb, sPre, t);
  __syncthreads();

  int e = blockIdx.x * 256 + t;
  if (e >= E) return;
  int src = ei[e];
  int dst = ei[E + e];
  int2 a = *(const int2*)&ea[2 * e];
  int pos = offs[dst] + sPre[dst >> 10] + rank[e];
  recs[pos] = (u32)src | ((u32)(a.x * 6 + a.y) << 26);
}

// =====================================================================
// k_gather: pipelined. 8 lanes/edge (64-B quarter row), 8-lane group
// owns one node. recs regs hoisted OUT of the q-loop (loaded once).
// Two B8 buffers: batch t+1's 8 gather loads are issued before batch t
// is consumed -> ~16 loads in flight per wave (r2 post-mortem: the 55us
// wall was <2 loads in flight due to VGPR starvation at 36 regs).
// =====================================================================
struct B8 { uint2 x[8]; u32 r[8]; };

__device__ __forceinline__ void issue8(B8& b, u32 rv, int grp,
                                       const u32* __restrict__ xq, int sub) {
  #pragma unroll
  for (int k = 0; k < 8; k++) {
    u32 r = __shfl(rv, grp + k);
    b.r[k] = r;
    b.x[k] = *(const uint2*)&xq[(size_t)(r & 0x3ffffffu) * 16 + sub * 2];
  }
}

__device__ __forceinline__ void acc8(float* a, const B8& b,
                                     const u32* __restrict__ sEq,
                                     int sub, int dleft) {
  #pragma unroll
  for (int k = 0; k < 8; k++) {
    if (k < dleft) {
      uint2 e = *(const uint2*)&sEq[(b.r[k] >> 26) * 18 + sub * 2];
      uint2 x = b.x[k];
      a[0] += bl(x.x) + bl(e.x);  a[1] += bh(x.x) + bh(e.x);
      a[2] += bl(x.y) + bl(e.y);  a[3] += bh(x.y) + bh(e.y);
    }
  }
}

__global__ __launch_bounds__(256, 4) void k_gather(
    const int* __restrict__ offs, const int* __restrict__ bsum, int nb,
    const u32* __restrict__ recs, const u32* __restrict__ embP,
    const u32* __restrict__ xencQ, u32* __restrict__ aggbQ, int N, int E)
{
  const int ES = 18;                  // u32 stride per combo row (8B-aligned)
  __shared__ u32 sE[4 * 36 * ES];     // 10.4 KB packed bf16 emb
  __shared__ int sPre[256];

  const int t = threadIdx.x;
  for (int i = t; i < 4 * 36 * 16; i += 256) {
    int qc = i >> 4, s = i & 15;
    sE[qc * ES + s] = embP[i];
  }
  if (t < 64) wave_scan_bsum(bsum, nb, sPre, t);
  __syncthreads();

  const int lane = t & 63, wave = t >> 6;
  const int grp = lane & 56, sub = lane & 7;
  const int v = blockIdx.x * 32 + wave * 8 + (lane >> 3);
  const bool vok = v < N;
  const int vc = vok ? v : N - 1;
  const int beg = offs[vc] + sPre[vc >> 10];
  const int end = (vc == N - 1) ? E : (offs[vc + 1] + sPre[(vc + 1) >> 10]);
  const int d = vok ? end - beg : 0;

  // recs are quarter-independent: load once, reuse across q-loop.
  u32 rv0 = 0, rv1 = 0, rv2 = 0, rv3 = 0;
  if (d > 0)  rv0 = recs[min(beg + sub, end - 1)];
  if (d > 8)  rv1 = recs[min(beg + 8 + sub, end - 1)];
  if (d > 16) rv2 = recs[min(beg + 16 + sub, end - 1)];
  if (d > 24) rv3 = recs[min(beg + 24 + sub, end - 1)];

  #pragma unroll 1
  for (int q = 0; q < 4; q++) {
    const u32* xq = xencQ + (size_t)q * N * 16;   // 16 u32 per row
    const u32* sEq = &sE[q * 36 * ES];

    // self-loop (combo 5*6+0 = 30)
    uint2 xs = *(const uint2*)&xq[(size_t)vc * 16 + sub * 2];
    uint2 es = *(const uint2*)&sEq[30 * ES + sub * 2];
    float a[4];
    a[0] = bl(xs.x) + bl(es.x);  a[1] = bh(xs.x) + bh(es.x);
    a[2] = bl(xs.y) + bl(es.y);  a[3] = bh(xs.y) + bh(es.y);

    if (d > 0) {
      B8 bA, bB;
      issue8(bA, rv0, grp, xq, sub);
      if (d > 8) issue8(bB, rv1, grp, xq, sub);
      acc8(a, bA, sEq, sub, d);
      if (d > 8) {
        if (d > 16) issue8(bA, rv2, grp, xq, sub);
        acc8(a, bB, sEq, sub, d - 8);
        if (d > 16) {
          if (d > 24) issue8(bB, rv3, grp, xq, sub);
          acc8(a, bA, sEq, sub, d - 16);
          if (d > 24) {
            acc8(a, bB, sEq, sub, d - 24);
            for (int j0 = 32; j0 < d; j0 += 8) {       // rare tail
              u32 rvt = recs[min(beg + j0 + sub, end - 1)];
              issue8(bA, rvt, grp, xq, sub);
              acc8(a, bA, sEq, sub, d - j0);
            }
          }
        }
      }
    }

    if (vok) {
      uint2 o;
      o.x = pk2(a[0], a[1]);
      o.y = pk2(a[2], a[3]);
      *(uint2*)&aggbQ[((size_t)q * N + vc) * 16 + sub * 2] = o;
    }
  }
}

// =====================================================================
// k_mlp (fused): out = silu(agg @ W1 + b1) @ W2 + b2
// A-fragments read from quarter-major aggbQ (ks == quarter).
// =====================================================================
__global__ __launch_bounds__(256) void k_mlp(
    const u16* __restrict__ aggbQ, const u16* __restrict__ W1T,
    const float* __restrict__ b1, const u16* __restrict__ W2T,
    const float* __restrict__ b2, float* __restrict__ out, int N)
{
  const int SK = 136;
  __shared__ u16 sW[128 * SK];      // 34 KB: W1 n-half, then W2 k-half
  __shared__ u16 sH[128 * SK];      // 34 KB: h tile (128 rows x 128 cols)
  __shared__ float sB1[256];
  __shared__ float sB2[128];

  const int t = threadIdx.x;
  const int lane = t & 63, wave = t >> 6, quad = lane >> 4, l16 = lane & 15;
  const int m0 = blockIdx.x * 128 + wave * 32;

  if (t < 128) sB2[t] = b2[t];
  sB1[t] = b1[t];

  // A fragments (aggb rows) loaded once, reused across both halves
  union { uint4 q; short8 s; } a[2][4];
  #pragma unroll
  for (int mr = 0; mr < 2; mr++) {
    int row = min(m0 + mr * 16 + l16, N - 1);
    #pragma unroll
    for (int ks = 0; ks < 4; ks++)
      a[mr][ks].q = *(const uint4*)&aggbQ[((size_t)ks * N + row) * 32 + quad * 8];
  }

  f32x4 acc2[2][8];
  #pragma unroll
  for (int mr = 0; mr < 2; mr++)
    #pragma unroll
    for (int nt = 0; nt < 8; nt++) acc2[mr][nt] = (f32x4){0.f, 0.f, 0.f, 0.f};

  for (int half = 0; half < 2; half++) {
    // stage W1 n-half
    #pragma unroll
    for (int j = 0; j < 8; j++) {
      int i = t + 256 * j;
      int n = i >> 4, k8 = i & 15;
      *(uint4*)&sW[n * SK + k8 * 8] =
          *(const uint4*)&W1T[(size_t)(half * 128 + n) * 128 + k8 * 8];
    }
    __syncthreads();

    // GEMM1: h_half = agg @ W1half
    f32x4 acc1[2][8];
    #pragma unroll
    for (int mr = 0; mr < 2; mr++)
      #pragma unroll
      for (int nt = 0; nt < 8; nt++) acc1[mr][nt] = (f32x4){0.f, 0.f, 0.f, 0.f};

    #pragma unroll
    for (int ks = 0; ks < 4; ks++) {
      const int k0 = ks * 32 + quad * 8;
      #pragma unroll
      for (int nt = 0; nt < 8; nt++) {
        short8 b = *(const short8*)&sW[(nt * 16 + l16) * SK + k0];
        acc1[0][nt] = __builtin_amdgcn_mfma_f32_16x16x32_bf16(a[0][ks].s, b, acc1[0][nt], 0, 0, 0);
        acc1[1][nt] = __builtin_amdgcn_mfma_f32_16x16x32_bf16(a[1][ks].s, b, acc1[1][nt], 0, 0, 0);
      }
    }

    // silu + C-layout -> A-layout via LDS tile (wave-local rows)
    #pragma unroll
    for (int mr = 0; mr < 2; mr++)
      #pragma unroll
      for (int nt = 0; nt < 8; nt++) {
        int col = nt * 16 + l16;
        float bias = sB1[half * 128 + col];
        #pragma unroll
        for (int r = 0; r < 4; r++) {
          float z = acc1[mr][nt][r] + bias;
          float s = z / (1.f + __expf(-z));
          sH[(wave * 32 + mr * 16 + quad * 4 + r) * SK + col] = f2b(s);
        }
      }
    __syncthreads();          // all waves done reading sW (GEMM1)

    // re-stage sW with W2 k-half
    #pragma unroll
    for (int j = 0; j < 8; j++) {
      int i = t + 256 * j;
      int n = i >> 4, k8 = i & 15;
      *(uint4*)&sW[n * SK + k8 * 8] =
          *(const uint4*)&W2T[(size_t)n * 256 + half * 128 + k8 * 8];
    }
    __syncthreads();

    // GEMM2: out_acc += h_half @ W2_khalf
    #pragma unroll
    for (int ks = 0; ks < 4; ks++) {
      const int k0 = ks * 32 + quad * 8;
      union { uint4 q; short8 s; } ah[2];
      #pragma unroll
      for (int mr = 0; mr < 2; mr++)
        ah[mr].q = *(const uint4*)&sH[(wave * 32 + mr * 16 + l16) * SK + k0];
      #pragma unroll
      for (int nt = 0; nt < 8; nt++) {
        short8 b = *(const short8*)&sW[(nt * 16 + l16) * SK + k0];
        acc2[0][nt] = __builtin_amdgcn_mfma_f32_16x16x32_bf16(ah[0].s, b, acc2[0][nt], 0, 0, 0);
        acc2[1][nt] = __builtin_amdgcn_mfma_f32_16x16x32_bf16(ah[1].s, b, acc2[1][nt], 0, 0, 0);
      }
    }
    __syncthreads();          // all waves done reading sW before next half
  }

  #pragma unroll
  for (int mr = 0; mr < 2; mr++)
    #pragma unroll
    for (int nt = 0; nt < 8; nt++) {
      int col = nt * 16 + l16;
      float bias = sB2[col];
      #pragma unroll
      for (int r = 0; r < 4; r++) {
        int row = m0 + mr * 16 + quad * 4 + r;
        if (row < N) out[(size_t)row * 128 + col] = acc2[mr][nt][r] + bias;
      }
    }
}

// =====================================================================
extern "C" void kernel_launch(void* const* d_in, const int* in_sizes, int n_in,
                              void* d_out, int out_size, void* d_ws, size_t ws_size,
                              hipStream_t stream) {
  const float* x    = (const float*)d_in[0];
  const int*   ei   = (const int*)d_in[1];
  const int*   ea   = (const int*)d_in[2];
  const float* pa   = (const float*)d_in[3];
  const float* Wenc = (const float*)d_in[4];
  const float* e1   = (const float*)d_in[5];
  const float* e2   = (const float*)d_in[6];
  const float* W1   = (const float*)d_in[7];
  const float* b1   = (const float*)d_in[8];
  const float* W2   = (const float*)d_in[9];
  const float* b2   = (const float*)d_in[10];
  float* out = (float*)d_out;

  const int N = in_sizes[0] / 128;
  const int E = in_sizes[1] / 2;

  char* ws = (char*)d_ws;
  size_t off = 0;
  auto alloc = [&](size_t bytes) {
    void* p = ws + off;
    off = (off + bytes + 255) & ~(size_t)255;
    return p;
  };
  u16*   xencQ  = (u16*)  alloc((size_t)N * 128 * 2);  // quarter-major
  u32*   aggbQ  = (u32*)  alloc((size_t)N * 64 * 4);   // quarter-major bf16
  int*   cnt    = (int*)  alloc((size_t)N * 4);
  int*   offs   = (int*)  alloc((size_t)(N + 1) * 4);
  int*   rank   = (int*)  alloc((size_t)E * 4);
  int*   bsum   = (int*)  alloc(256 * 4);
  u32*   recs   = (u32*)  alloc((size_t)(E + 64) * 4); // +pad for clamped reads
  u16*   W1T    = (u16*)  alloc(256 * 128 * 2);
  u16*   W2T    = (u16*)  alloc(128 * 256 * 2);
  u32*   embP   = (u32*)  alloc(2304 * 4);             // [4][36][16] packed

  const int encBlocks    = (N + 127) / 128;
  const int edgeBlocks   = (E + 255) / 256;
  const int nb           = (N + 1023) / 1024;
  const int gatherBlocks = (N + 31) / 32;

  hipMemsetAsync(cnt, 0, (size_t)N * 4, stream);
  k_enc_count<<<encBlocks + edgeBlocks, 256, 0, stream>>>(
      x, pa, Wenc, xencQ, N, ei, cnt, rank, E, encBlocks);
  k_scanW<<<nb + 265, 256, 0, stream>>>(
      cnt, offs, bsum, N, nb, W1, W2, e1, e2, W1T, W2T, embP);
  k_fill<<<edgeBlocks, 256, 0, stream>>>(ei, ea, offs, rank, bsum, nb, recs, E);
  k_gather<<<gatherBlocks, 256, 0, stream>>>(
      offs, bsum, nb, recs, embP, (const u32*)xencQ, aggbQ, N, E);
  k_mlp<<<encBlocks, 256, 0, stream>>>(
      (const u16*)aggbQ, W1T, b1, W2T, b2, out, N);
}

// Round 4
// 214.592 us; speedup vs baseline: 1.1082x; 1.0436x over previous
//
#include <hip/hip_runtime.h>

typedef unsigned short u16;
typedef unsigned int   u32;
typedef __attribute__((ext_vector_type(8))) short short8;   // 8 bf16 (4 VGPRs)
typedef __attribute__((ext_vector_type(4))) float f32x4;    // MFMA C/D

// ---- bf16 helpers (bf16 = top 16 bits of fp32; half-up rounding) ----
__device__ __forceinline__ float bl(u32 u){ union{u32 i; float f;} c; c.i = u << 16; return c.f; }
__device__ __forceinline__ float bh(u32 u){ union{u32 i; float f;} c; c.i = u & 0xffff0000u; return c.f; }
__device__ __forceinline__ u16 f2b(float f){
  union{float f; u32 i;} c; c.f = f;
  return (u16)((c.i + 0x8000u) >> 16);
}
__device__ __forceinline__ u32 pk2(float a, float b){
  union{float f; u32 i;} x, y; x.f = a; y.f = b;
  return ((x.i + 0x8000u) >> 16) | ((y.i + 0x8000u) & 0xffff0000u);
}

// one-wave exclusive scan of bsum[0..nb) into sPre (call with t < 64)
__device__ __forceinline__ void wave_scan_bsum(
    const int* __restrict__ bsum, int nb, int* __restrict__ sPre, int t)
{
  int carry = 0;
  for (int c0 = 0; c0 < nb; c0 += 64) {
    int idx = c0 + t;
    int b = (idx < nb) ? bsum[idx] : 0;
    int v = b;
    #pragma unroll
    for (int d = 1; d < 64; d <<= 1) {
      int u = __shfl_up(v, d);
      if (t >= d) v += u;
    }
    if (idx < nb) sPre[idx] = carry + v - b;   // exclusive
    carry += __shfl(v, 63);
  }
}

// =====================================================================
// k_pre (replaces memset): WencT bf16 [128n][128k], embP [4][36][16]
// packed bf16 emb table, cnt zeroing.
// =====================================================================
__global__ __launch_bounds__(256) void k_pre(
    const float* __restrict__ Wenc, const float* __restrict__ e1,
    const float* __restrict__ e2, u16* __restrict__ WencT,
    u32* __restrict__ embP, int* __restrict__ cnt, int N)
{
  int i = blockIdx.x * 256 + threadIdx.x;
  if (i < 16384) {                        // WencT: [128 n][128 k]
    int n = i >> 7, k = i & 127;
    WencT[i] = f2b(Wenc[k * 128 + n]);
  } else if (i < 16384 + 2304) {          // embP: [4 q][36 c][16 u32]
    int j = i - 16384;
    int q = j / 576, rem = j - q * 576;
    int c = rem >> 4, s = rem & 15;
    int c1 = c / 6, c2 = c - c1 * 6;
    int col = q * 32 + s * 2;
    embP[j] = pk2(e1[c1 * 128 + col]     + e2[c2 * 128 + col],
                  e1[c1 * 128 + col + 1] + e2[c2 * 128 + col + 1]);
  } else {
    int j = i - 16384 - 2304;
    if (j < N) cnt[j] = 0;
  }
}

// =====================================================================
// k_enc_count: blocks [0, encBlocks) -> xencQ = bf16(PReLU(x) @ W_enc),
//              stored QUARTER-MAJOR: xencQ[q][node][32 cols].
//              blocks [encBlocks,..) -> degree histogram + per-edge rank
// =====================================================================
__global__ __launch_bounds__(256) void k_enc_count(
    const float* __restrict__ x, const float* __restrict__ pa,
    const u16* __restrict__ WT, u16* __restrict__ xencQ, int N,
    const int* __restrict__ ei, int* __restrict__ cnt,
    int* __restrict__ rank, int E, int encBlocks)
{
  if ((int)blockIdx.x >= encBlocks) {
    int e = ((int)blockIdx.x - encBlocks) * 256 + threadIdx.x;
    if (e < E) rank[e] = atomicAdd(&cnt[ei[E + e]], 1);
    return;
  }

  const int SK = 136, NT = 8;
  __shared__ u16 sB[128 * SK];           // 34 KB

  const int t = threadIdx.x;
  #pragma unroll
  for (int j = 0; j < 8; j++) {          // vectorized stage from WencT
    int i = t + 256 * j;
    int n = i >> 4, k8 = i & 15;
    *(uint4*)&sB[n * SK + k8 * 8] = *(const uint4*)&WT[n * 128 + k8 * 8];
  }
  __syncthreads();

  const float slope = pa[0];
  const int lane = t & 63, wave = t >> 6, quad = lane >> 4, l16 = lane & 15;
  const int m0 = blockIdx.x * 128 + wave * 32;
  if (m0 >= N) return;

  f32x4 acc[2][NT];
  #pragma unroll
  for (int mr = 0; mr < 2; mr++)
    #pragma unroll
    for (int nt = 0; nt < NT; nt++) acc[mr][nt] = (f32x4){0.f, 0.f, 0.f, 0.f};

  #pragma unroll
  for (int ks = 0; ks < 4; ks++) {
    const int k0 = ks * 32 + quad * 8;
    union { u32 u[4]; short8 s; } a[2];
    #pragma unroll
    for (int mr = 0; mr < 2; mr++) {
      int row = m0 + mr * 16 + l16; row = min(row, N - 1);
      const float4* ap = (const float4*)&x[(size_t)row * 128 + k0];
      float4 f0 = ap[0], f1 = ap[1];
      float v0 = f0.x > 0.f ? f0.x : slope * f0.x;
      float v1 = f0.y > 0.f ? f0.y : slope * f0.y;
      float v2 = f0.z > 0.f ? f0.z : slope * f0.z;
      float v3 = f0.w > 0.f ? f0.w : slope * f0.w;
      float v4 = f1.x > 0.f ? f1.x : slope * f1.x;
      float v5 = f1.y > 0.f ? f1.y : slope * f1.y;
      float v6 = f1.z > 0.f ? f1.z : slope * f1.z;
      float v7 = f1.w > 0.f ? f1.w : slope * f1.w;
      a[mr].u[0] = pk2(v0, v1); a[mr].u[1] = pk2(v2, v3);
      a[mr].u[2] = pk2(v4, v5); a[mr].u[3] = pk2(v6, v7);
    }
    #pragma unroll
    for (int nt = 0; nt < NT; nt++) {
      short8 b = *(const short8*)&sB[(nt * 16 + l16) * SK + k0];
      acc[0][nt] = __builtin_amdgcn_mfma_f32_16x16x32_bf16(a[0].s, b, acc[0][nt], 0, 0, 0);
      acc[1][nt] = __builtin_amdgcn_mfma_f32_16x16x32_bf16(a[1].s, b, acc[1][nt], 0, 0, 0);
    }
  }

  #pragma unroll
  for (int mr = 0; mr < 2; mr++)
    #pragma unroll
    for (int nt = 0; nt < NT; nt++) {
      int col = nt * 16 + l16;
      int q = col >> 5, cq = col & 31;
      #pragma unroll
      for (int r = 0; r < 4; r++) {
        int row = m0 + mr * 16 + quad * 4 + r;
        if (row < N)
          xencQ[((size_t)q * N + row) * 32 + cq] = f2b(acc[mr][nt][r]);
      }
    }
}

// =====================================================================
// k_scanW: blocks [0,nb)  -> per-1024-chunk exclusive scan of cnt.
//          blocks [nb,..) -> W1T / W2T transpose.
// =====================================================================
__global__ __launch_bounds__(256) void k_scanW(
    const int* __restrict__ cnt, int* __restrict__ offs,
    int* __restrict__ bsum, int n, int nb,
    const float* __restrict__ W1, const float* __restrict__ W2,
    u16* __restrict__ W1T, u16* __restrict__ W2T)
{
  if ((int)blockIdx.x >= nb) {
    int i = ((int)blockIdx.x - nb) * 256 + threadIdx.x;   // [0, 65536)
    if (i < 32768) {                 // W1T: [256 n][128 k]
      int nn = i >> 7, k = i & 127;
      W1T[i] = f2b(W1[k * 256 + nn]);
    } else {                         // W2T: [128 n][256 k]
      int j = i - 32768;
      int nn = j >> 8, k = j & 255;
      W2T[j] = f2b(W2[k * 128 + nn]);
    }
    return;
  }

  __shared__ int sS[256];
  const int b = blockIdx.x, t = threadIdx.x;
  const int i0 = b * 1024 + t * 4;
  int4 v = make_int4(0, 0, 0, 0);
  if (i0 + 3 < n) v = *(const int4*)&cnt[i0];
  else {
    if (i0     < n) v.x = cnt[i0];
    if (i0 + 1 < n) v.y = cnt[i0 + 1];
    if (i0 + 2 < n) v.z = cnt[i0 + 2];
  }
  int s = v.x + v.y + v.z + v.w;
  sS[t] = s;
  __syncthreads();
  for (int d = 1; d < 256; d <<= 1) {
    int val = (t >= d) ? sS[t - d] : 0;
    __syncthreads();
    sS[t] += val;
    __syncthreads();
  }
  int ex = sS[t] - s;
  if (t == 255) bsum[b] = sS[t];
  int o0 = ex, o1 = o0 + v.x, o2 = o1 + v.y, o3 = o2 + v.z;
  if (i0     < n) offs[i0]     = o0;
  if (i0 + 1 < n) offs[i0 + 1] = o1;
  if (i0 + 2 < n) offs[i0 + 2] = o2;
  if (i0 + 3 < n) offs[i0 + 3] = o3;
}

// =====================================================================
// k_fill: atomic-free scatter of packed edge records (uses rank).
// rec = src | (a1*6+a2) << 26.  Adds bsum prefix inline.
// =====================================================================
__global__ __launch_bounds__(256) void k_fill(
    const int* __restrict__ ei, const int* __restrict__ ea,
    const int* __restrict__ offs, const int* __restrict__ rank,
    const int* __restrict__ bsum, int nb,
    u32* __restrict__ recs, int E)
{
  __shared__ int sPre[256];
  const int t = threadIdx.x;
  if (t < 64) wave_scan_bsum(bsum, nb, sPre, t);
  __syncthreads();

  int e = blockIdx.x * 256 + t;
  if (e >= E) return;
  int src = ei[e];
  int dst = ei[E + e];
  int2 a = *(const int2*)&ea[2 * e];
  int pos = offs[dst] + sPre[dst >> 10] + rank[e];
  recs[pos] = (u32)src | ((u32)(a.x * 6 + a.y) << 26);
}

// =====================================================================
// k_gather: GRID-LEVEL quarter phases. q = blockIdx / nodeBlocks, so
// all q=0 blocks dispatch before q=1 blocks -> live xenc working set is
// ~1 quarter (3.2 MB) -> per-XCD-L2 resident (r3 post-mortem: per-block
// q-loop made each CU cohort touch all 12.8 MB -> 108 MB HBM refetch).
// 8 lanes/edge, 8-lane group owns one node, 2-deep B8 pipeline.
// =====================================================================
struct B8 { uint2 x[8]; u32 r[8]; };

__device__ __forceinline__ void issue8(B8& b, u32 rv, int grp,
                                       const u32* __restrict__ xq, int sub) {
  #pragma unroll
  for (int k = 0; k < 8; k++) {
    u32 r = __shfl(rv, grp + k);
    b.r[k] = r;
    b.x[k] = *(const uint2*)&xq[(size_t)(r & 0x3ffffffu) * 16 + sub * 2];
  }
}

__device__ __forceinline__ void acc8(float* a, const B8& b,
                                     const u32* __restrict__ sEq,
                                     int sub, int dleft) {
  #pragma unroll
  for (int k = 0; k < 8; k++) {
    if (k < dleft) {
      uint2 e = *(const uint2*)&sEq[(b.r[k] >> 26) * 18 + sub * 2];
      uint2 x = b.x[k];
      a[0] += bl(x.x) + bl(e.x);  a[1] += bh(x.x) + bh(e.x);
      a[2] += bl(x.y) + bl(e.y);  a[3] += bh(x.y) + bh(e.y);
    }
  }
}

__global__ __launch_bounds__(256) void k_gather(
    const int* __restrict__ offs, const int* __restrict__ bsum, int nb,
    const u32* __restrict__ recs, const u32* __restrict__ embP,
    const u32* __restrict__ xencQ, u32* __restrict__ aggbQ,
    int N, int E, int nodeBlocks)
{
  const int ES = 18;                  // u32 stride per combo row
  __shared__ u32 sE[36 * ES];         // 2.6 KB: ONE quarter's emb
  __shared__ int sPre[256];

  const int t = threadIdx.x;
  const int q = (int)blockIdx.x / nodeBlocks;
  const int nbid = (int)blockIdx.x - q * nodeBlocks;

  for (int i = t; i < 576; i += 256) {       // embP[q*576 + c*16 + s]
    int c = i >> 4, s = i & 15;
    sE[c * ES + s] = embP[q * 576 + i];
  }
  if (t < 64) wave_scan_bsum(bsum, nb, sPre, t);
  __syncthreads();

  const int lane = t & 63, wave = t >> 6;
  const int grp = lane & 56, sub = lane & 7;
  const int v = nbid * 32 + wave * 8 + (lane >> 3);
  const bool vok = v < N;
  const int vc = vok ? v : N - 1;
  const int beg = offs[vc] + sPre[vc >> 10];
  const int end = (vc == N - 1) ? E : (offs[vc + 1] + sPre[(vc + 1) >> 10]);
  const int d = vok ? end - beg : 0;

  u32 rv0 = 0, rv1 = 0, rv2 = 0, rv3 = 0;
  if (d > 0)  rv0 = recs[min(beg + sub, end - 1)];
  if (d > 8)  rv1 = recs[min(beg + 8 + sub, end - 1)];
  if (d > 16) rv2 = recs[min(beg + 16 + sub, end - 1)];
  if (d > 24) rv3 = recs[min(beg + 24 + sub, end - 1)];

  const u32* xq = xencQ + (size_t)q * N * 16;   // 16 u32 per row

  // self-loop (combo 5*6+0 = 30)
  uint2 xs = *(const uint2*)&xq[(size_t)vc * 16 + sub * 2];
  uint2 es = *(const uint2*)&sE[30 * ES + sub * 2];
  float a[4];
  a[0] = bl(xs.x) + bl(es.x);  a[1] = bh(xs.x) + bh(es.x);
  a[2] = bl(xs.y) + bl(es.y);  a[3] = bh(xs.y) + bh(es.y);

  if (d > 0) {
    B8 bA, bB;
    issue8(bA, rv0, grp, xq, sub);
    if (d > 8) issue8(bB, rv1, grp, xq, sub);
    acc8(a, bA, sE, sub, d);
    if (d > 8) {
      if (d > 16) issue8(bA, rv2, grp, xq, sub);
      acc8(a, bB, sE, sub, d - 8);
      if (d > 16) {
        if (d > 24) issue8(bB, rv3, grp, xq, sub);
        acc8(a, bA, sE, sub, d - 16);
        if (d > 24) {
          acc8(a, bB, sE, sub, d - 24);
          for (int j0 = 32; j0 < d; j0 += 8) {       // rare tail
            u32 rvt = recs[min(beg + j0 + sub, end - 1)];
            issue8(bA, rvt, grp, xq, sub);
            acc8(a, bA, sE, sub, d - j0);
          }
        }
      }
    }
  }

  if (vok) {
    uint2 o;
    o.x = pk2(a[0], a[1]);
    o.y = pk2(a[2], a[3]);
    *(uint2*)&aggbQ[((size_t)q * N + vc) * 16 + sub * 2] = o;
  }
}

// =====================================================================
// k_mlp (fused): out = silu(agg @ W1 + b1) @ W2 + b2
// A-fragments read from quarter-major aggbQ (ks == quarter).
// =====================================================================
__global__ __launch_bounds__(256) void k_mlp(
    const u16* __restrict__ aggbQ, const u16* __restrict__ W1T,
    const float* __restrict__ b1, const u16* __restrict__ W2T,
    const float* __restrict__ b2, float* __restrict__ out, int N)
{
  const int SK = 136;
  __shared__ u16 sW[128 * SK];      // 34 KB: W1 n-half, then W2 k-half
  __shared__ u16 sH[128 * SK];      // 34 KB: h tile (128 rows x 128 cols)
  __shared__ float sB1[256];
  __shared__ float sB2[128];

  const int t = threadIdx.x;
  const int lane = t & 63, wave = t >> 6, quad = lane >> 4, l16 = lane & 15;
  const int m0 = blockIdx.x * 128 + wave * 32;

  if (t < 128) sB2[t] = b2[t];
  sB1[t] = b1[t];

  // A fragments (aggb rows) loaded once, reused across both halves
  union { uint4 q; short8 s; } a[2][4];
  #pragma unroll
  for (int mr = 0; mr < 2; mr++) {
    int row = min(m0 + mr * 16 + l16, N - 1);
    #pragma unroll
    for (int ks = 0; ks < 4; ks++)
      a[mr][ks].q = *(const uint4*)&aggbQ[((size_t)ks * N + row) * 32 + quad * 8];
  }

  f32x4 acc2[2][8];
  #pragma unroll
  for (int mr = 0; mr < 2; mr++)
    #pragma unroll
    for (int nt = 0; nt < 8; nt++) acc2[mr][nt] = (f32x4){0.f, 0.f, 0.f, 0.f};

  for (int half = 0; half < 2; half++) {
    // stage W1 n-half
    #pragma unroll
    for (int j = 0; j < 8; j++) {
      int i = t + 256 * j;
      int n = i >> 4, k8 = i & 15;
      *(uint4*)&sW[n * SK + k8 * 8] =
          *(const uint4*)&W1T[(size_t)(half * 128 + n) * 128 + k8 * 8];
    }
    __syncthreads();

    // GEMM1: h_half = agg @ W1half
    f32x4 acc1[2][8];
    #pragma unroll
    for (int mr = 0; mr < 2; mr++)
      #pragma unroll
      for (int nt = 0; nt < 8; nt++) acc1[mr][nt] = (f32x4){0.f, 0.f, 0.f, 0.f};

    #pragma unroll
    for (int ks = 0; ks < 4; ks++) {
      const int k0 = ks * 32 + quad * 8;
      #pragma unroll
      for (int nt = 0; nt < 8; nt++) {
        short8 b = *(const short8*)&sW[(nt * 16 + l16) * SK + k0];
        acc1[0][nt] = __builtin_amdgcn_mfma_f32_16x16x32_bf16(a[0][ks].s, b, acc1[0][nt], 0, 0, 0);
        acc1[1][nt] = __builtin_amdgcn_mfma_f32_16x16x32_bf16(a[1][ks].s, b, acc1[1][nt], 0, 0, 0);
      }
    }

    // silu + C-layout -> A-layout via LDS tile (wave-local rows)
    #pragma unroll
    for (int mr = 0; mr < 2; mr++)
      #pragma unroll
      for (int nt = 0; nt < 8; nt++) {
        int col = nt * 16 + l16;
        float bias = sB1[half * 128 + col];
        #pragma unroll
        for (int r = 0; r < 4; r++) {
          float z = acc1[mr][nt][r] + bias;
          float s = z / (1.f + __expf(-z));
          sH[(wave * 32 + mr * 16 + quad * 4 + r) * SK + col] = f2b(s);
        }
      }
    __syncthreads();          // all waves done reading sW (GEMM1)

    // re-stage sW with W2 k-half
    #pragma unroll
    for (int j = 0; j < 8; j++) {
      int i = t + 256 * j;
      int n = i >> 4, k8 = i & 15;
      *(uint4*)&sW[n * SK + k8 * 8] =
          *(const uint4*)&W2T[(size_t)n * 256 + half * 128 + k8 * 8];
    }
    __syncthreads();

    // GEMM2: out_acc += h_half @ W2_khalf
    #pragma unroll
    for (int ks = 0; ks < 4; ks++) {
      const int k0 = ks * 32 + quad * 8;
      union { uint4 q; short8 s; } ah[2];
      #pragma unroll
      for (int mr = 0; mr < 2; mr++)
        ah[mr].q = *(const uint4*)&sH[(wave * 32 + mr * 16 + l16) * SK + k0];
      #pragma unroll
      for (int nt = 0; nt < 8; nt++) {
        short8 b = *(const short8*)&sW[(nt * 16 + l16) * SK + k0];
        acc2[0][nt] = __builtin_amdgcn_mfma_f32_16x16x32_bf16(ah[0].s, b, acc2[0][nt], 0, 0, 0);
        acc2[1][nt] = __builtin_amdgcn_mfma_f32_16x16x32_bf16(ah[1].s, b, acc2[1][nt], 0, 0, 0);
      }
    }
    __syncthreads();          // all waves done reading sW before next half
  }

  #pragma unroll
  for (int mr = 0; mr < 2; mr++)
    #pragma unroll
    for (int nt = 0; nt < 8; nt++) {
      int col = nt * 16 + l16;
      float bias = sB2[col];
      #pragma unroll
      for (int r = 0; r < 4; r++) {
        int row = m0 + mr * 16 + quad * 4 + r;
        if (row < N) out[(size_t)row * 128 + col] = acc2[mr][nt][r] + bias;
      }
    }
}

// =====================================================================
extern "C" void kernel_launch(void* const* d_in, const int* in_sizes, int n_in,
                              void* d_out, int out_size, void* d_ws, size_t ws_size,
                              hipStream_t stream) {
  const float* x    = (const float*)d_in[0];
  const int*   ei   = (const int*)d_in[1];
  const int*   ea   = (const int*)d_in[2];
  const float* pa   = (const float*)d_in[3];
  const float* Wenc = (const float*)d_in[4];
  const float* e1   = (const float*)d_in[5];
  const float* e2   = (const float*)d_in[6];
  const float* W1   = (const float*)d_in[7];
  const float* b1   = (const float*)d_in[8];
  const float* W2   = (const float*)d_in[9];
  const float* b2   = (const float*)d_in[10];
  float* out = (float*)d_out;

  const int N = in_sizes[0] / 128;
  const int E = in_sizes[1] / 2;

  char* ws = (char*)d_ws;
  size_t off = 0;
  auto alloc = [&](size_t bytes) {
    void* p = ws + off;
    off = (off + bytes + 255) & ~(size_t)255;
    return p;
  };
  u16*   xencQ  = (u16*)  alloc((size_t)N * 128 * 2);  // quarter-major
  u32*   aggbQ  = (u32*)  alloc((size_t)N * 64 * 4);   // quarter-major bf16
  int*   cnt    = (int*)  alloc((size_t)N * 4);
  int*   offs   = (int*)  alloc((size_t)(N + 1) * 4);
  int*   rank   = (int*)  alloc((size_t)E * 4);
  int*   bsum   = (int*)  alloc(256 * 4);
  u32*   recs   = (u32*)  alloc((size_t)(E + 64) * 4); // +pad for clamped reads
  u16*   WencT  = (u16*)  alloc(128 * 128 * 2);
  u16*   W1T    = (u16*)  alloc(256 * 128 * 2);
  u16*   W2T    = (u16*)  alloc(128 * 256 * 2);
  u32*   embP   = (u32*)  alloc(2304 * 4);             // [4][36][16] packed

  const int encBlocks    = (N + 127) / 128;
  const int edgeBlocks   = (E + 255) / 256;
  const int nb           = (N + 1023) / 1024;
  const int nodeBlocks   = (N + 31) / 32;
  const int preBlocks    = (16384 + 2304 + N + 255) / 256;

  k_pre<<<preBlocks, 256, 0, stream>>>(Wenc, e1, e2, WencT, embP, cnt, N);
  k_enc_count<<<encBlocks + edgeBlocks, 256, 0, stream>>>(
      x, pa, WencT, xencQ, N, ei, cnt, rank, E, encBlocks);
  k_scanW<<<nb + 256, 256, 0, stream>>>(
      cnt, offs, bsum, N, nb, W1, W2, W1T, W2T);
  k_fill<<<edgeBlocks, 256, 0, stream>>>(ei, ea, offs, rank, bsum, nb, recs, E);
  k_gather<<<4 * nodeBlocks, 256, 0, stream>>>(
      offs, bsum, nb, recs, embP, (const u32*)xencQ, aggbQ, N, E, nodeBlocks);
  k_mlp<<<encBlocks, 256, 0, stream>>>(
      (const u16*)aggbQ, W1T, b1, W2T, b2, out, N);
}